// Round 9
// baseline (75.779 us; speedup 1.0000x reference)
//
#include <hip/hip_runtime.h>

// Geometry: inputs [B=32, H=128, W=128, C=128] fp32, STRIDE=2.
// comps[k] = inputs[:, i::2, j::2, :], k = i*2 + j.
// Out 0: comps[argmax L2] = [32,64,64,128] fp32 (16,777,216 elems). Out 1: index (float).

#define IN_F4     16777216   // 32*128*128*128 / 4
#define OUT_F4     4194304   // 32*64*64*128 / 4
#define OUT_ELEMS 16777216
#define SNBLK     8192       // sums grid
#define SNT       2097152    // 8192 * 256 = 2^21 threads
#define GNBLK     2048       // gather grid
#define GNT       524288     // 2048 * 256 = 2^19 threads

typedef float nfloat4 __attribute__((ext_vector_type(4)));  // native vec for nontemporal builtin

// Pass 1: sums of squares, ascending sweep (ends with input tail L3-hot; the
// descending gather of the PREVIOUS replay left the front hot — synergistic).
// v = tid + u*SNT (SNT = 2^21): bit5(v) = bit5(tid) (w-parity), bit12(v) =
// bit12(tid) (h-parity) — each thread owns exactly one polyphase component.
// R9 A/B vs R8: 2x blocks, 8 loads/thread, LB(256,4) -> >=16 waves/CU,
// ~256 KB in flight per CU (2x R8). Plain epilogue (R7 lesson: no fence/ticket).
__global__ void __launch_bounds__(256, 4) sums_kernel(const float4* __restrict__ in,
                                                      float* __restrict__ partials) {
    const int tid  = blockIdx.x * 256 + threadIdx.x;
    const int lane = threadIdx.x & 63;
    const int wave = threadIdx.x >> 6;
    float acc = 0.f;
#pragma unroll
    for (int u = 0; u < 8; ++u) {
        float4 x = in[tid + u * SNT];
        acc += x.x * x.x + x.y * x.y + x.z * x.z + x.w * x.w;
    }
    // Reduce each 32-lane half independently (xor 1..16 keeps bit5 fixed).
    for (int off = 16; off >= 1; off >>= 1)
        acc += __shfl_xor(acc, off, 64);
    __shared__ float plds[4][2];   // [wave][wpar]
    if (lane == 0)  plds[wave][0] = acc;
    if (lane == 32) plds[wave][1] = acc;
    __syncthreads();
    if (threadIdx.x < 2) {
        // partials entry e = blockIdx*2 + wpar: k(e) = 2*bit5(e) + bit0(e)
        // (bit5(e) = bit4(blockIdx) = bit12(tid) = h-parity).
        partials[blockIdx.x * 2 + threadIdx.x] =
            plds[0][threadIdx.x] + plds[1][threadIdx.x] +
            plds[2][threadIdx.x] + plds[3][threadIdx.x];
    }
}

// Pass 2 (fused): every block redundantly reduces all 16384 partials with
// IDENTICAL double-precision arithmetic -> identical argmax in every block.
// Then gathers comps[k] -> out in DESCENDING address order (reads the L3-hot
// tail of the sums sweep first) with non-temporal stores (output never
// re-read; keep it from evicting L3-resident input).
__global__ void __launch_bounds__(256, 2) pick_gather_kernel(const float4* __restrict__ in,
                                                             float4* __restrict__ out,
                                                             const float* __restrict__ partials) {
    const int lane = threadIdx.x & 63;
    const int wave = threadIdx.x >> 6;
    __shared__ double klds[4][4];  // [wave][k]
    __shared__ int sidx;
    {
        // Entry e = t + 256*m: bits 0..7 of e fixed per thread ->
        // k = 2*bit5(t) + bit0(t), constant per thread.
        const int t = threadIdx.x;
        double s = 0.0;
        for (int m = 0; m < 2 * SNBLK; m += 256) s += (double)partials[t + m];
        // Collapse lane bits 1..4 (xor 2,4,8,16 preserve bit0 and bit5).
        for (int off = 2; off <= 16; off <<= 1)
            s += __shfl_xor(s, off, 64);
        const int kk = 2 * ((lane >> 5) & 1) + (lane & 1);
        if (lane == 0 || lane == 1 || lane == 32 || lane == 33) klds[wave][kk] = s;
        __syncthreads();
        if (t == 0) {
            double best = -1.0;
            int bi = 0;
            for (int q = 0; q < 4; ++q) {
                double sq = klds[0][q] + klds[1][q] + klds[2][q] + klds[3][q];
                if (sq > best) { best = sq; bi = q; }   // first-max, matches jnp.argmax
            }
            sidx = bi;
            if (blockIdx.x == 0) ((float*)out)[OUT_ELEMS] = (float)bi;
        }
        __syncthreads();
    }
    const int k = sidx;
    const int i = k >> 1;
    const int j = k & 1;
    const int tid = blockIdx.x * 256 + threadIdx.x;
#pragma unroll
    for (int m = 0; m < 8; ++m) {
        int o  = OUT_F4 - 1 - (tid + m * GNT);   // descending sweep: hot tail first
        int c4 = o & 31;
        int wq = (o >> 5) & 63;
        int hq = (o >> 11) & 63;
        int b  = o >> 17;
        int vin = b * 524288 + (2 * hq + i) * 4096 + (2 * wq + j) * 32 + c4;
        float4 val = in[vin];
        nfloat4 nval = { val.x, val.y, val.z, val.w };
        __builtin_nontemporal_store(nval, reinterpret_cast<nfloat4*>(&out[o]));
    }
}

extern "C" void kernel_launch(void* const* d_in, const int* in_sizes, int n_in,
                              void* d_out, int out_size, void* d_ws, size_t ws_size,
                              hipStream_t stream) {
    const float4* in = (const float4*)d_in[0];
    float4* out = (float4*)d_out;
    float* partials = (float*)d_ws;   // 16384 floats, fully rewritten every call

    sums_kernel<<<SNBLK, 256, 0, stream>>>(in, partials);
    pick_gather_kernel<<<GNBLK, 256, 0, stream>>>(in, out, partials);
}

// Round 10
// 75.141 us; speedup vs baseline: 1.0085x; 1.0085x over previous
//
#include <hip/hip_runtime.h>

// Geometry: inputs [B=32, H=128, W=128, C=128] fp32, STRIDE=2.
// comps[k] = inputs[:, i::2, j::2, :], k = i*2 + j.
// Out 0: comps[argmax L2] = [32,64,64,128] fp32 (16,777,216 elems). Out 1: index (float).

#define IN_F4     16777216   // 32*128*128*128 / 4
#define OUT_F4     4194304   // 32*64*64*128 / 4
#define OUT_ELEMS 16777216
#define SNBLK     4096       // sums grid
#define SNT       1048576    // 4096 * 256 = 2^20 threads
#define GNBLK     2048       // gather grid
#define GNT       524288     // 2048 * 256 = 2^19 threads

typedef float nfloat4 __attribute__((ext_vector_type(4)));  // native vec for nontemporal builtin

// Pass 1: sums of squares, ascending sweep (ends with input tail L3-hot; the
// descending gather of the PREVIOUS replay left the front hot — synergistic).
// v = tid + u*SNT (SNT = 2^20): bit5(v) = bit5(tid) (w-parity), bit12(v) =
// bit12(tid) (h-parity) — each thread owns exactly one polyphase component.
// R10 A/B vs R8: LB(256,2) -> LB(256,4). R8: 8 waves/CU x 16 loads = 128 KB/CU
// in flight; R9: 16 waves x 8 loads = 128 KB (null A/B, explained). This round:
// 16 waves x 16 loads = 256 KB/CU. VGPR est ~90 < 128 cap -> no spill.
__global__ void __launch_bounds__(256, 4) sums_kernel(const float4* __restrict__ in,
                                                      float* __restrict__ partials) {
    const int tid  = blockIdx.x * 256 + threadIdx.x;
    const int lane = threadIdx.x & 63;
    const int wave = threadIdx.x >> 6;
    float acc = 0.f;
#pragma unroll
    for (int u = 0; u < 16; ++u) {
        float4 x = in[tid + u * SNT];
        acc += x.x * x.x + x.y * x.y + x.z * x.z + x.w * x.w;
    }
    // Reduce each 32-lane half independently (xor 1..16 keeps bit5 fixed).
    for (int off = 16; off >= 1; off >>= 1)
        acc += __shfl_xor(acc, off, 64);
    __shared__ float plds[4][2];   // [wave][wpar]
    if (lane == 0)  plds[wave][0] = acc;
    if (lane == 32) plds[wave][1] = acc;
    __syncthreads();
    if (threadIdx.x < 2) {
        // partials entry e = blockIdx*2 + wpar: k(e) = 2*bit5(e) + bit0(e)
        // (bit5(e) = bit4(blockIdx) = bit12(tid) = h-parity).
        partials[blockIdx.x * 2 + threadIdx.x] =
            plds[0][threadIdx.x] + plds[1][threadIdx.x] +
            plds[2][threadIdx.x] + plds[3][threadIdx.x];
    }
}

// Pass 2 (fused): every block redundantly reduces all 8192 partials with
// IDENTICAL double-precision arithmetic -> identical argmax in every block.
// Then gathers comps[k] -> out in DESCENDING address order (reads the L3-hot
// tail of the sums sweep first) with non-temporal stores (output never
// re-read; keep it from evicting L3-resident input).
__global__ void __launch_bounds__(256, 2) pick_gather_kernel(const float4* __restrict__ in,
                                                             float4* __restrict__ out,
                                                             const float* __restrict__ partials) {
    const int lane = threadIdx.x & 63;
    const int wave = threadIdx.x >> 6;
    __shared__ double klds[4][4];  // [wave][k]
    __shared__ int sidx;
    {
        // Entry e = t + 256*m: bits 0..7 of e fixed per thread ->
        // k = 2*bit5(t) + bit0(t), constant per thread.
        const int t = threadIdx.x;
        double s = 0.0;
        for (int m = 0; m < 2 * SNBLK; m += 256) s += (double)partials[t + m];
        // Collapse lane bits 1..4 (xor 2,4,8,16 preserve bit0 and bit5).
        for (int off = 2; off <= 16; off <<= 1)
            s += __shfl_xor(s, off, 64);
        const int kk = 2 * ((lane >> 5) & 1) + (lane & 1);
        if (lane == 0 || lane == 1 || lane == 32 || lane == 33) klds[wave][kk] = s;
        __syncthreads();
        if (t == 0) {
            double best = -1.0;
            int bi = 0;
            for (int q = 0; q < 4; ++q) {
                double sq = klds[0][q] + klds[1][q] + klds[2][q] + klds[3][q];
                if (sq > best) { best = sq; bi = q; }   // first-max, matches jnp.argmax
            }
            sidx = bi;
            if (blockIdx.x == 0) ((float*)out)[OUT_ELEMS] = (float)bi;
        }
        __syncthreads();
    }
    const int k = sidx;
    const int i = k >> 1;
    const int j = k & 1;
    const int tid = blockIdx.x * 256 + threadIdx.x;
#pragma unroll
    for (int m = 0; m < 8; ++m) {
        int o  = OUT_F4 - 1 - (tid + m * GNT);   // descending sweep: hot tail first
        int c4 = o & 31;
        int wq = (o >> 5) & 63;
        int hq = (o >> 11) & 63;
        int b  = o >> 17;
        int vin = b * 524288 + (2 * hq + i) * 4096 + (2 * wq + j) * 32 + c4;
        float4 val = in[vin];
        nfloat4 nval = { val.x, val.y, val.z, val.w };
        __builtin_nontemporal_store(nval, reinterpret_cast<nfloat4*>(&out[o]));
    }
}

extern "C" void kernel_launch(void* const* d_in, const int* in_sizes, int n_in,
                              void* d_out, int out_size, void* d_ws, size_t ws_size,
                              hipStream_t stream) {
    const float4* in = (const float4*)d_in[0];
    float4* out = (float4*)d_out;
    float* partials = (float*)d_ws;   // 8192 floats, fully rewritten every call

    sums_kernel<<<SNBLK, 256, 0, stream>>>(in, partials);
    pick_gather_kernel<<<GNBLK, 256, 0, stream>>>(in, out, partials);
}